// Round 7
// baseline (90.154 us; speedup 1.0000x reference)
//
#include <hip/hip_runtime.h>
#include <hip/hip_bf16.h>

#define FDIM 1024
#define BROWS 16384
#define DELTA_C 0.3f
#define LAMB_C 0.0005f

typedef __bf16 bf8v __attribute__((ext_vector_type(8)));
typedef float f4v __attribute__((ext_vector_type(4)));
typedef unsigned short u16;
typedef u16 u16x8 __attribute__((ext_vector_type(8)));

// ws layout (bytes):
//   0    : f32 wsf[16]     (0=hinge)
//   64   : f32 colsum[1024]  (wsf+16)
//   4160 : f32 pabs[128]
//   4672 : f32 psq[128]
//   8192 : f32 rowacc[16384]  (64KB)
//   131072 : wb  bf16 tiled [128 kslot][1024 n][8]   (2MB)  wb[(ks*1024+n)*8+e] = w[ks*8+e][n]
//   131072+2MB : sktb bf16 tiled [128 kslot][16384 m][8] (32MB) sktb[(ks*16384+m)*8+e] = skt[m][ks*8+e]
#define WS_PABS_OFF 4160
#define WS_PSQ_OFF 4672
#define WS_ROWACC_OFF 8192
#define WS_WB_OFF 131072
#define WS_SKTB_OFF (131072 + (1u << 21))
#define WS_NEED_FULL ((size_t)WS_SKTB_OFF + ((size_t)1 << 25))

__device__ __forceinline__ u16 f2bf(float f) {
  unsigned u = __builtin_bit_cast(unsigned, f);
  u += 0x7fffu + ((u >> 16) & 1u);
  return (u16)(u >> 16);
}

__device__ __forceinline__ void gload_lds16(const void* g, void* l) {
  __builtin_amdgcn_global_load_lds(
      (const __attribute__((address_space(1))) unsigned int*)g,
      (__attribute__((address_space(3))) unsigned int*)l, 16, 0, 0);
}

// ---- merged prep: blocks [0,128) do W; blocks [128, 128+2048) do A ----
// A-blocks are XCD-aligned with the consumer: block writing sktb m-slice mt
// runs on XCD (mt>>3), matching hofel_main's swizzle -> stage reads hit local L2.
template <bool DO_A>
__global__ __launch_bounds__(256) void prep_all(const float* __restrict__ w,
                                                const float* __restrict__ skt,
                                                float* __restrict__ colsum,
                                                float* __restrict__ pabs,
                                                float* __restrict__ psq,
                                                u16* __restrict__ wb,
                                                u16* __restrict__ sktb) {
  __shared__ char smem_u[17440];
  const int t = threadIdx.x;
  const int bid = blockIdx.x;

  if (bid < 128) {
    u16(*tile)[1024] = (u16(*)[1024])smem_u;  // 16KB
    float* red = (float*)(smem_u + 16384);
    const int b = bid;
    const int k0 = b * 8;
    const int col = t * 4;

    float cs0 = 0.f, cs1 = 0.f, cs2 = 0.f, cs3 = 0.f;
    float aacc = 0.f, sacc = 0.f;
#pragma unroll
    for (int i = 0; i < 8; ++i) {
      const int gk = k0 + i;
      const float4 v = *(const float4*)(w + (size_t)gk * FDIM + col);
      ushort4 bb;
      bb.x = f2bf(v.x); bb.y = f2bf(v.y); bb.z = f2bf(v.z); bb.w = f2bf(v.w);
      *(ushort4*)(&tile[i][col]) = bb;
      cs0 += v.x; cs1 += v.y; cs2 += v.z; cs3 += v.w;
      const float d0 = v.x - (gk == col + 0 ? 1.f : 0.f);
      const float d1 = v.y - (gk == col + 1 ? 1.f : 0.f);
      const float d2 = v.z - (gk == col + 2 ? 1.f : 0.f);
      const float d3 = v.w - (gk == col + 3 ? 1.f : 0.f);
      aacc += fabsf(d0) + fabsf(d1) + fabsf(d2) + fabsf(d3);
      sacc += d0 * d0 + d1 * d1 + d2 * d2 + d3 * d3;
    }
    atomicAdd(&colsum[col + 0], cs0);
    atomicAdd(&colsum[col + 1], cs1);
    atomicAdd(&colsum[col + 2], cs2);
    atomicAdd(&colsum[col + 3], cs3);
#pragma unroll
    for (int off = 1; off < 64; off <<= 1) {
      aacc += __shfl_xor(aacc, off);
      sacc += __shfl_xor(sacc, off);
    }
    const int wid = t >> 6;
    if ((t & 63) == 0) { red[wid] = aacc; red[4 + wid] = sacc; }
    __syncthreads();
    if (t == 0) pabs[b] = red[0] + red[1] + red[2] + red[3];
    if (t == 1) psq[b] = red[4] + red[5] + red[6] + red[7];
#pragma unroll
    for (int j = 0; j < 4; ++j) {
      const int n = col + j;
      u16x8 pk;
#pragma unroll
      for (int e = 0; e < 8; ++e) pk[e] = tile[e][n];
      *(u16x8*)(wb + ((size_t)b * FDIM + n) * 8) = pk;
    }
  } else if constexpr (DO_A) {
    u16(*tile)[136] = (u16(*)[136])smem_u;  // 64 x 136 u16
    const int bidp = bid - 128;             // 0..2047
    // XCD-aligned remap: ab's m-range XCD target = ab>>8; dispatch XCD = bid%8 = bidp&7
    const int ab = ((bidp & 7) << 8) | (bidp >> 3);
    const int mb = ab >> 3;
    const int kb = ab & 7;
    const int m0 = mb * 64, k0 = kb * 128;
#pragma unroll
    for (int i = 0; i < 8; ++i) {
      const int fid = i * 256 + t;
      const int ml = fid >> 5;
      const int c4 = fid & 31;
      const float4 v = *(const float4*)(skt + (size_t)(m0 + ml) * FDIM + k0 + c4 * 4);
      ushort4 b;
      b.x = f2bf(v.x); b.y = f2bf(v.y); b.z = f2bf(v.z); b.w = f2bf(v.w);
      *(ushort4*)(&tile[ml][c4 * 4]) = b;
    }
    __syncthreads();
    const int ks0 = k0 >> 3;
#pragma unroll
    for (int i = 0; i < 4; ++i) {
      const int uid = i * 256 + t;
      const int si = uid >> 6;
      const int ml = uid & 63;
      const u16x8 pk = *(const u16x8*)(&tile[ml][si * 8]);
      *(u16x8*)(sktb + ((size_t)(ks0 + si) * BROWS + m0 + ml) * 8) = pk;
    }
  }
}

// ---- main: T = skt @ w, BM=256 BN=256 BK=32, 4-buffer depth-3 2-phase pipeline ----
// 512 threads = 8 waves (2M x 4N), per-wave 128x64 output (acc 8x4).
// Per buffer (32KB): A bytes [0,16K) = [4 kslot][256 m][16B]; B [16K,32K) = [4][256][16B]
#define MM(mi, ni, a, b) \
  acc[mi][ni] = __builtin_amdgcn_mfma_f32_16x16x32_bf16(a, b, acc[mi][ni], 0, 0, 0)

template <bool PRE>
__global__ __launch_bounds__(512, 2) void hofel_main(
    const float* __restrict__ skt, const float* __restrict__ imgp,
    const float* __restrict__ imgn, const u16* __restrict__ wb,
    const u16* __restrict__ sktb, const float* __restrict__ colsum,
    float* __restrict__ rowacc) {
  __shared__ u16 ldsT[4][16384];  // 4 x 32KB (PRE uses all 4; fallback uses [0])
  __shared__ float lds_cs[256];

  const int t = threadIdx.x;
  const int lane = t & 63;
  const int wid = t >> 6;  // 0..7
  const int l15 = lane & 15;
  const int l4 = lane >> 4;

  // XCD swizzle (256 % 8 == 0, bijective): XCD x gets mt in [x*8, x*8+8)
  const int swz = (blockIdx.x & 7) * 32 + (blockIdx.x >> 3);
  const int mt = swz >> 2, nt = swz & 3;
  const int m0 = mt * 256, n0 = nt * 256;

  const int wr = wid >> 2, wc = wid & 3;
  const int wm = wr * 128, wn = wc * 64;

  const int aoff = l4 * 4096 + (wm + l15) * 16;
  const int boff = l4 * 4096 + (wn + l15) * 16;

  f4v acc[8][4];
#pragma unroll
  for (int mi = 0; mi < 8; ++mi)
#pragma unroll
    for (int ni = 0; ni < 4; ++ni) {
      f4v z = {0.f, 0.f, 0.f, 0.f};
      acc[mi][ni] = z;
    }

  // stage one 32KB K32-tile: exactly 4 wave-level gload_lds per wave.
  auto stage = [&](int buf, int kt) {
#pragma unroll
    for (int r = 0; r < 2; ++r) {  // A region
      const int o = r * 8192 + wid * 1024;
      const int ol = o + lane * 16;
      const int s = ol >> 12;
      const int m = (ol >> 4) & 255;
      gload_lds16((const char*)(sktb + ((size_t)(kt * 4 + s) * BROWS + m0 + m) * 8),
                  (char*)ldsT[buf] + o);
    }
#pragma unroll
    for (int r = 0; r < 2; ++r) {  // B region
      const int o = r * 8192 + wid * 1024;
      const int ol = o + lane * 16;
      const int s = ol >> 12;
      const int n = (ol >> 4) & 255;
      gload_lds16((const char*)(wb + ((size_t)(kt * 4 + s) * FDIM + n0 + n) * 8),
                  (char*)ldsT[buf] + 16384 + o);
    }
  };

  if constexpr (PRE) {
    // prologue: colsum -> LDS, drain, prefetch tiles 0..2 (12 loads in flight)
    if (t < 256) lds_cs[t] = colsum[n0 + t];
    asm volatile("s_waitcnt vmcnt(0) lgkmcnt(0)" ::: "memory");
    __builtin_amdgcn_sched_barrier(0);
    stage(0, 0);
    stage(1, 1);
    stage(2, 2);
    asm volatile("s_waitcnt vmcnt(8)" ::: "memory");  // tile 0 landed
    __builtin_amdgcn_s_barrier();
    __builtin_amdgcn_sched_barrier(0);

    for (int kt = 0; kt < 32; ++kt) {
      const char* ldsA = (const char*)ldsT[kt & 3];
      const char* ldsB = ldsA + 16384;

      // ---- phase 1: bF0..3 + aF0..3 reads, stage(kt+3), 16 MFMA (mi 0..3) ----
      bf8v bF0 = *(const bf8v*)(ldsB + boff);
      bf8v bF1 = *(const bf8v*)(ldsB + boff + 256);
      bf8v bF2 = *(const bf8v*)(ldsB + boff + 512);
      bf8v bF3 = *(const bf8v*)(ldsB + boff + 768);
      bf8v a0 = *(const bf8v*)(ldsA + aoff);
      bf8v a1 = *(const bf8v*)(ldsA + aoff + 256);
      bf8v a2 = *(const bf8v*)(ldsA + aoff + 512);
      bf8v a3 = *(const bf8v*)(ldsA + aoff + 768);
      if (kt < 29) stage((kt + 3) & 3, kt + 3);  // overwrites tile kt-1's buffer (safe)
      asm volatile("s_waitcnt lgkmcnt(0)" ::: "memory");
      __builtin_amdgcn_sched_barrier(0);
      __builtin_amdgcn_s_setprio(1);
      MM(0, 0, a0, bF0); MM(0, 1, a0, bF1); MM(0, 2, a0, bF2); MM(0, 3, a0, bF3);
      MM(1, 0, a1, bF0); MM(1, 1, a1, bF1); MM(1, 2, a1, bF2); MM(1, 3, a1, bF3);
      MM(2, 0, a2, bF0); MM(2, 1, a2, bF1); MM(2, 2, a2, bF2); MM(2, 3, a2, bF3);
      MM(3, 0, a3, bF0); MM(3, 1, a3, bF1); MM(3, 2, a3, bF2); MM(3, 3, a3, bF3);
      __builtin_amdgcn_s_setprio(0);
      __builtin_amdgcn_s_barrier();
      __builtin_amdgcn_sched_barrier(0);

      // ---- phase 2: aF4..7 reads, 16 MFMA (mi 4..7) ----
      a0 = *(const bf8v*)(ldsA + aoff + 1024);
      a1 = *(const bf8v*)(ldsA + aoff + 1280);
      a2 = *(const bf8v*)(ldsA + aoff + 1536);
      a3 = *(const bf8v*)(ldsA + aoff + 1792);
      asm volatile("s_waitcnt lgkmcnt(0)" ::: "memory");
      __builtin_amdgcn_sched_barrier(0);
      __builtin_amdgcn_s_setprio(1);
      MM(4, 0, a0, bF0); MM(4, 1, a0, bF1); MM(4, 2, a0, bF2); MM(4, 3, a0, bF3);
      MM(5, 0, a1, bF0); MM(5, 1, a1, bF1); MM(5, 2, a1, bF2); MM(5, 3, a1, bF3);
      MM(6, 0, a2, bF0); MM(6, 1, a2, bF1); MM(6, 2, a2, bF2); MM(6, 3, a2, bF3);
      MM(7, 0, a3, bF0); MM(7, 1, a3, bF1); MM(7, 2, a3, bF2); MM(7, 3, a3, bF3);
      __builtin_amdgcn_s_setprio(0);

      // tile boundary: counted wait (never 0 until tail), then barrier
      if (kt < 29) {
        asm volatile("s_waitcnt vmcnt(8)" ::: "memory");  // tile kt+1 landed; kt+2,kt+3 in flight
      } else if (kt == 29) {
        asm volatile("s_waitcnt vmcnt(4)" ::: "memory");
      } else if (kt == 30) {
        asm volatile("s_waitcnt vmcnt(0)" ::: "memory");
      }
      if (kt < 31) __builtin_amdgcn_s_barrier();
      __builtin_amdgcn_sched_barrier(0);
    }
  } else {
    // ---- fallback (no workspace): single-buffer full-drain schedule ----
    if (t < 256) lds_cs[t] = colsum[n0 + t];
    for (int kt = 0; kt < 32; ++kt) {
      __syncthreads();
      // B via gload
#pragma unroll
      for (int r = 0; r < 2; ++r) {
        const int o = r * 8192 + wid * 1024;
        const int ol = o + lane * 16;
        const int s = ol >> 12;
        const int n = (ol >> 4) & 255;
        gload_lds16((const char*)(wb + ((size_t)(kt * 4 + s) * FDIM + n0 + n) * 8),
                    (char*)ldsT[0] + 16384 + o);
      }
      // A: f32 -> bf16 convert
      const int m = t >> 1, h = t & 1;
      const float* ap = skt + (size_t)(m0 + m) * FDIM + kt * 32 + h * 16;
#pragma unroll
      for (int q = 0; q < 2; ++q) {
        const float4 v0 = *(const float4*)(ap + q * 8);
        const float4 v1 = *(const float4*)(ap + q * 8 + 4);
        u16x8 pk;
        pk[0] = f2bf(v0.x); pk[1] = f2bf(v0.y); pk[2] = f2bf(v0.z); pk[3] = f2bf(v0.w);
        pk[4] = f2bf(v1.x); pk[5] = f2bf(v1.y); pk[6] = f2bf(v1.z); pk[7] = f2bf(v1.w);
        *(u16x8*)((char*)ldsT[0] + (h * 2 + q) * 4096 + m * 16) = pk;
      }
      __syncthreads();
      const char* ldsA = (const char*)ldsT[0];
      const char* ldsB = ldsA + 16384;
      bf8v bF0 = *(const bf8v*)(ldsB + boff);
      bf8v bF1 = *(const bf8v*)(ldsB + boff + 256);
      bf8v bF2 = *(const bf8v*)(ldsB + boff + 512);
      bf8v bF3 = *(const bf8v*)(ldsB + boff + 768);
#pragma unroll
      for (int mh = 0; mh < 8; mh += 4) {
        bf8v a0 = *(const bf8v*)(ldsA + aoff + (mh + 0) * 256);
        bf8v a1 = *(const bf8v*)(ldsA + aoff + (mh + 1) * 256);
        bf8v a2 = *(const bf8v*)(ldsA + aoff + (mh + 2) * 256);
        bf8v a3 = *(const bf8v*)(ldsA + aoff + (mh + 3) * 256);
        MM(mh + 0, 0, a0, bF0); MM(mh + 0, 1, a0, bF1); MM(mh + 0, 2, a0, bF2); MM(mh + 0, 3, a0, bF3);
        MM(mh + 1, 0, a1, bF0); MM(mh + 1, 1, a1, bF1); MM(mh + 1, 2, a1, bF2); MM(mh + 1, 3, a1, bF3);
        MM(mh + 2, 0, a2, bF0); MM(mh + 2, 1, a2, bF1); MM(mh + 2, 2, a2, bF2); MM(mh + 2, 3, a2, bF3);
        MM(mh + 3, 0, a3, bF0); MM(mh + 3, 1, a3, bF1); MM(mh + 3, 2, a3, bF2); MM(mh + 3, 3, a3, bF3);
      }
    }
  }

  // fused epilogue: rowacc[row] += sum_c (p-n)*(-2*T + (p+n)*colsum[c])
#pragma unroll
  for (int mi = 0; mi < 8; ++mi) {
#pragma unroll
    for (int rr = 0; rr < 4; ++rr) {
      const int row = m0 + wm + mi * 16 + l4 * 4 + rr;
      const float* pr = imgp + (size_t)row * FDIM + n0;
      const float* nr = imgn + (size_t)row * FDIM + n0;
      float s = 0.f;
#pragma unroll
      for (int ni = 0; ni < 4; ++ni) {
        const int cl = wn + ni * 16 + l15;
        const float T = acc[mi][ni][rr];
        const float p = pr[cl];
        const float q = nr[cl];
        s += (p - q) * (-2.f * T + (p + q) * lds_cs[cl]);
      }
#pragma unroll
      for (int off = 1; off < 16; off <<= 1) s += __shfl_xor(s, off);
      if (l15 == 0) atomicAdd(rowacc + row, s);
    }
  }
}

__global__ __launch_bounds__(1024) void hinge_reduce(const float* __restrict__ rowacc,
                                                     float* __restrict__ wsf) {
  __shared__ float part[16];
  const int t = threadIdx.x;
  const int id = blockIdx.x * 1024 + t;
  float v = fmaxf(DELTA_C + rowacc[id], 0.f);
#pragma unroll
  for (int off = 1; off < 64; off <<= 1) v += __shfl_xor(v, off);
  if ((t & 63) == 0) part[t >> 6] = v;
  __syncthreads();
  if (t < 16) {
    float x = part[t];
#pragma unroll
    for (int off = 1; off < 16; off <<= 1) x += __shfl_xor(x, off);
    if (t == 0) atomicAdd(&wsf[0], x);
  }
}

__global__ __launch_bounds__(128) void finalize_k(const float* __restrict__ wsf,
                                                  const float* __restrict__ pabs,
                                                  const float* __restrict__ psq,
                                                  float* __restrict__ out) {
  __shared__ float ra[2], rs[2];
  const int t = threadIdx.x;
  float a = pabs[t], s = psq[t];
#pragma unroll
  for (int off = 1; off < 64; off <<= 1) {
    a += __shfl_xor(a, off);
    s += __shfl_xor(s, off);
  }
  if ((t & 63) == 0) { ra[t >> 6] = a; rs[t >> 6] = s; }
  __syncthreads();
  if (t == 0)
    out[0] = wsf[0] * (1.f / (float)BROWS) +
             LAMB_C * ((ra[0] + ra[1]) + sqrtf(rs[0] + rs[1]));
}

extern "C" void kernel_launch(void* const* d_in, const int* in_sizes, int n_in,
                              void* d_out, int out_size, void* d_ws, size_t ws_size,
                              hipStream_t stream) {
  const float* skt  = (const float*)d_in[0];
  const float* imgp = (const float*)d_in[1];
  const float* imgn = (const float*)d_in[2];
  const float* w    = (const float*)d_in[3];

  float* wsf = (float*)d_ws;
  float* colsum = wsf + 16;
  float* pabs = (float*)((char*)d_ws + WS_PABS_OFF);
  float* psq = (float*)((char*)d_ws + WS_PSQ_OFF);
  float* rowacc = (float*)((char*)d_ws + WS_ROWACC_OFF);
  u16* wb = (u16*)((char*)d_ws + WS_WB_OFF);
  u16* sktb = (u16*)((char*)d_ws + WS_SKTB_OFF);
  float* out = (float*)d_out;

  // zero wsf + colsum + rowacc every call (harness doesn't re-poison)
  hipMemsetAsync(d_ws, 0, WS_ROWACC_OFF + BROWS * sizeof(float), stream);

  if (ws_size >= WS_NEED_FULL) {
    prep_all<true><<<128 + 2048, 256, 0, stream>>>(w, skt, colsum, pabs, psq, wb, sktb);
    hofel_main<true><<<256, 512, 0, stream>>>(skt, imgp, imgn, wb, sktb, colsum, rowacc);
  } else {
    prep_all<false><<<128, 256, 0, stream>>>(w, skt, colsum, pabs, psq, wb, sktb);
    hofel_main<false><<<256, 512, 0, stream>>>(skt, imgp, imgn, wb, sktb, colsum, rowacc);
  }

  hinge_reduce<<<16, 1024, 0, stream>>>(rowacc, wsf);
  finalize_k<<<1, 128, 0, stream>>>(wsf, pabs, psq, out);
}

// Round 8
// 86.765 us; speedup vs baseline: 1.0391x; 1.0391x over previous
//
#include <hip/hip_runtime.h>
#include <hip/hip_bf16.h>

#define FDIM 1024
#define BROWS 16384
#define DELTA_C 0.3f
#define LAMB_C 0.0005f

typedef __bf16 bf8v __attribute__((ext_vector_type(8)));
typedef float f4v __attribute__((ext_vector_type(4)));
typedef unsigned short u16;
typedef u16 u16x8 __attribute__((ext_vector_type(8)));

// ws layout (bytes):
//   0    : f32 wsf[16]     (0=hinge)
//   64   : f32 colsum[1024]  (wsf+16)
//   4160 : f32 pabs[128]
//   4672 : f32 psq[128]
//   8192 : f32 rowacc[16384]  (64KB)
//   131072 : wb  bf16 tiled [128 kslot][1024 n][8]   (2MB)  wb[(ks*1024+n)*8+e] = w[ks*8+e][n]
//   131072+2MB : sktb bf16 tiled [128 kslot][16384 m][8] (32MB) sktb[(ks*16384+m)*8+e] = skt[m][ks*8+e]
#define WS_PABS_OFF 4160
#define WS_PSQ_OFF 4672
#define WS_ROWACC_OFF 8192
#define WS_WB_OFF 131072
#define WS_SKTB_OFF (131072 + (1u << 21))
#define WS_NEED_FULL ((size_t)WS_SKTB_OFF + ((size_t)1 << 25))

__device__ __forceinline__ u16 f2bf(float f) {
  unsigned u = __builtin_bit_cast(unsigned, f);
  u += 0x7fffu + ((u >> 16) & 1u);
  return (u16)(u >> 16);
}

__device__ __forceinline__ void gload_lds16(const void* g, void* l) {
  __builtin_amdgcn_global_load_lds(
      (const __attribute__((address_space(1))) unsigned int*)g,
      (__attribute__((address_space(3))) unsigned int*)l, 16, 0, 0);
}

// ---- merged prep: blocks [0,128) do W; blocks [128, 128+2048) do A ----
template <bool DO_A>
__global__ __launch_bounds__(256) void prep_all(const float* __restrict__ w,
                                                const float* __restrict__ skt,
                                                float* __restrict__ colsum,
                                                float* __restrict__ pabs,
                                                float* __restrict__ psq,
                                                u16* __restrict__ wb,
                                                u16* __restrict__ sktb) {
  __shared__ char smem_u[17440];
  const int t = threadIdx.x;
  const int bid = blockIdx.x;

  if (bid < 128) {
    u16(*tile)[1024] = (u16(*)[1024])smem_u;  // 16KB
    float* red = (float*)(smem_u + 16384);
    const int b = bid;
    const int k0 = b * 8;
    const int col = t * 4;

    float cs0 = 0.f, cs1 = 0.f, cs2 = 0.f, cs3 = 0.f;
    float aacc = 0.f, sacc = 0.f;
#pragma unroll
    for (int i = 0; i < 8; ++i) {
      const int gk = k0 + i;
      const float4 v = *(const float4*)(w + (size_t)gk * FDIM + col);
      ushort4 bb;
      bb.x = f2bf(v.x); bb.y = f2bf(v.y); bb.z = f2bf(v.z); bb.w = f2bf(v.w);
      *(ushort4*)(&tile[i][col]) = bb;
      cs0 += v.x; cs1 += v.y; cs2 += v.z; cs3 += v.w;
      const float d0 = v.x - (gk == col + 0 ? 1.f : 0.f);
      const float d1 = v.y - (gk == col + 1 ? 1.f : 0.f);
      const float d2 = v.z - (gk == col + 2 ? 1.f : 0.f);
      const float d3 = v.w - (gk == col + 3 ? 1.f : 0.f);
      aacc += fabsf(d0) + fabsf(d1) + fabsf(d2) + fabsf(d3);
      sacc += d0 * d0 + d1 * d1 + d2 * d2 + d3 * d3;
    }
    atomicAdd(&colsum[col + 0], cs0);
    atomicAdd(&colsum[col + 1], cs1);
    atomicAdd(&colsum[col + 2], cs2);
    atomicAdd(&colsum[col + 3], cs3);
#pragma unroll
    for (int off = 1; off < 64; off <<= 1) {
      aacc += __shfl_xor(aacc, off);
      sacc += __shfl_xor(sacc, off);
    }
    const int wid = t >> 6;
    if ((t & 63) == 0) { red[wid] = aacc; red[4 + wid] = sacc; }
    __syncthreads();
    if (t == 0) pabs[b] = red[0] + red[1] + red[2] + red[3];
    if (t == 1) psq[b] = red[4] + red[5] + red[6] + red[7];
#pragma unroll
    for (int j = 0; j < 4; ++j) {
      const int n = col + j;
      u16x8 pk;
#pragma unroll
      for (int e = 0; e < 8; ++e) pk[e] = tile[e][n];
      *(u16x8*)(wb + ((size_t)b * FDIM + n) * 8) = pk;
    }
  } else if constexpr (DO_A) {
    u16(*tile)[136] = (u16(*)[136])smem_u;  // 64 x 136 u16
    const int ab = bid - 128;
    const int mb = ab >> 3;
    const int kb = ab & 7;
    const int m0 = mb * 64, k0 = kb * 128;
#pragma unroll
    for (int i = 0; i < 8; ++i) {
      const int fid = i * 256 + t;
      const int ml = fid >> 5;
      const int c4 = fid & 31;
      const float4 v = *(const float4*)(skt + (size_t)(m0 + ml) * FDIM + k0 + c4 * 4);
      ushort4 b;
      b.x = f2bf(v.x); b.y = f2bf(v.y); b.z = f2bf(v.z); b.w = f2bf(v.w);
      *(ushort4*)(&tile[ml][c4 * 4]) = b;
    }
    __syncthreads();
    const int ks0 = k0 >> 3;
#pragma unroll
    for (int i = 0; i < 4; ++i) {
      const int uid = i * 256 + t;
      const int si = uid >> 6;
      const int ml = uid & 63;
      const u16x8 pk = *(const u16x8*)(&tile[ml][si * 8]);
      *(u16x8*)(sktb + ((size_t)(ks0 + si) * BROWS + m0 + ml) * 8) = pk;
    }
  }
}

// ---- main: T = skt @ w, BM=256 BN=128 BK=32, 2-buffer schedule (r5, proven) ----
// 512 threads = 8 waves (4M x 2N), per-wave 64x64 output.
// Per buffer (24KB): A bytes [0,16K) = [4 kslot][256 m][16B]; B [16K,24K) = [4][128][16B]
template <bool PRE>
__global__ __launch_bounds__(512, 4) void hofel_main(
    const float* __restrict__ skt, const float* __restrict__ imgp,
    const float* __restrict__ imgn, const u16* __restrict__ wb,
    const u16* __restrict__ sktb, const float* __restrict__ colsum,
    float* __restrict__ rowacc) {
  __shared__ u16 ldsT[2][12288];  // 2 x 24KB; reused as epilogue scratch
  __shared__ float lds_cs[128];

  const int t = threadIdx.x;
  const int lane = t & 63;
  const int wid = t >> 6;  // 0..7
  const int l15 = lane & 15;
  const int l4 = lane >> 4;

  // XCD swizzle: 512 blocks, XCD x -> mt in [x*8, x*8+8)
  const int swz = (blockIdx.x & 7) * 64 + (blockIdx.x >> 3);
  const int mt = swz >> 3, nt = swz & 7;
  const int m0 = mt * 256, n0 = nt * 128;

  const int wr = wid >> 1, wc = wid & 1;
  const int wm = wr * 64, wn = wc * 64;

  f4v acc[4][4];
#pragma unroll
  for (int mi = 0; mi < 4; ++mi)
#pragma unroll
    for (int ni = 0; ni < 4; ++ni) {
      f4v z = {0.f, 0.f, 0.f, 0.f};
      acc[mi][ni] = z;
    }

  auto stage = [&](int buf, int kt) {
    if constexpr (PRE) {
#pragma unroll
      for (int r = 0; r < 3; ++r) {
        const int o = r * 8192 + wid * 1024;  // wave-uniform LDS byte offset
        const int ol = o + lane * 16;
        const char* src;
        if (ol < 16384) {  // A region: [4][256][16B]
          const int s = ol >> 12;
          const int m = (ol >> 4) & 255;
          src = (const char*)(sktb + ((size_t)(kt * 4 + s) * BROWS + m0 + m) * 8);
        } else {  // B region: [4][128][16B]
          const int o2 = ol - 16384;
          const int s = o2 >> 11;
          const int n = (o2 >> 4) & 127;
          src = (const char*)(wb + ((size_t)(kt * 4 + s) * FDIM + n0 + n) * 8);
        }
        gload_lds16(src, (char*)ldsT[buf] + o);
      }
    } else {
      // B via global_load_lds
      {
        const int o = wid * 1024;
        const int ol = o + lane * 16;
        const int s = ol >> 11;
        const int n = (ol >> 4) & 127;
        gload_lds16((const char*)(wb + ((size_t)(kt * 4 + s) * FDIM + n0 + n) * 8),
                    (char*)ldsT[buf] + 16384 + o);
      }
      // A: f32 -> bf16 conversion
      const int m = t >> 1, h = t & 1;
      const float* ap = skt + (size_t)(m0 + m) * FDIM + kt * 32 + h * 16;
#pragma unroll
      for (int q = 0; q < 2; ++q) {
        const float4 v0 = *(const float4*)(ap + q * 8);
        const float4 v1 = *(const float4*)(ap + q * 8 + 4);
        u16x8 pk;
        pk[0] = f2bf(v0.x); pk[1] = f2bf(v0.y); pk[2] = f2bf(v0.z); pk[3] = f2bf(v0.w);
        pk[4] = f2bf(v1.x); pk[5] = f2bf(v1.y); pk[6] = f2bf(v1.z); pk[7] = f2bf(v1.w);
        *(u16x8*)((char*)ldsT[buf] + (h * 2 + q) * 4096 + m * 16) = pk;
      }
    }
  };

  // prologue
  stage(0, 0);
  if (t < 128) lds_cs[t] = colsum[n0 + t];
  __syncthreads();

  int cur = 0;
  for (int kt = 0; kt < 32; ++kt) {
    if (kt < 31) stage(cur ^ 1, kt + 1);  // issue next-tile loads (hidden under MFMA)

    const char* bufb = (const char*)ldsT[cur];
    bf8v aF[4], bF[4];
#pragma unroll
    for (int mi = 0; mi < 4; ++mi)
      aF[mi] = *(const bf8v*)(bufb + l4 * 4096 + (wm + mi * 16 + l15) * 16);
#pragma unroll
    for (int ni = 0; ni < 4; ++ni)
      bF[ni] = *(const bf8v*)(bufb + 16384 + l4 * 2048 + (wn + ni * 16 + l15) * 16);
#pragma unroll
    for (int mi = 0; mi < 4; ++mi)
#pragma unroll
      for (int ni = 0; ni < 4; ++ni)
        acc[mi][ni] = __builtin_amdgcn_mfma_f32_16x16x32_bf16(aF[mi], bF[ni], acc[mi][ni], 0, 0, 0);

    __syncthreads();
    cur ^= 1;
  }

  // ---- vectorized epilogue via per-wave LDS transpose ----
  // Per mi-chunk: dump acc[mi] (16 rows x 64 cols) to per-wave scratch, then
  // read T as b128 and imgp/imgn as float4 (row-contiguous, coalesced).
  {
    float(*eT)[68] = (float(*)[68])((char*)ldsT + wid * 4352);  // 16 x 68 f32
    const int r = l15;       // row this lane reduces
    const int qb = l4;       // base col-quad
#pragma unroll
    for (int mi = 0; mi < 4; ++mi) {
#pragma unroll
      for (int ni = 0; ni < 4; ++ni)
#pragma unroll
        for (int rr = 0; rr < 4; ++rr)
          eT[l4 * 4 + rr][ni * 16 + l15] = acc[mi][ni][rr];
      // per-wave private scratch: LDS ops are in-order within a wave; the
      // compiler inserts the lgkm wait before dependent reads.
      const int rowg = m0 + wm + mi * 16 + r;
      const float* pr = imgp + (size_t)rowg * FDIM + n0 + wn;
      const float* nr = imgn + (size_t)rowg * FDIM + n0 + wn;
      float part = 0.f;
#pragma unroll
      for (int i = 0; i < 4; ++i) {
        const int q = qb + 4 * i;  // col-quad 0..15
        const f4v T = *(const f4v*)&eT[r][q * 4];
        const float4 p = *(const float4*)(pr + q * 4);
        const float4 n = *(const float4*)(nr + q * 4);
        const f4v cs = *(const f4v*)&lds_cs[wn + q * 4];
        part += (p.x - n.x) * (-2.f * T[0] + (p.x + n.x) * cs[0]);
        part += (p.y - n.y) * (-2.f * T[1] + (p.y + n.y) * cs[1]);
        part += (p.z - n.z) * (-2.f * T[2] + (p.z + n.z) * cs[2]);
        part += (p.w - n.w) * (-2.f * T[3] + (p.w + n.w) * cs[3]);
      }
      part += __shfl_xor(part, 16);
      part += __shfl_xor(part, 32);
      if (lane < 16) atomicAdd(rowacc + rowg, part);
      __syncthreads();  // cheap: keeps waves' scratch phases aligned & orders reuse
    }
  }
}

__global__ __launch_bounds__(1024) void hinge_reduce(const float* __restrict__ rowacc,
                                                     float* __restrict__ wsf) {
  __shared__ float part[16];
  const int t = threadIdx.x;
  const int id = blockIdx.x * 1024 + t;
  float v = fmaxf(DELTA_C + rowacc[id], 0.f);
#pragma unroll
  for (int off = 1; off < 64; off <<= 1) v += __shfl_xor(v, off);
  if ((t & 63) == 0) part[t >> 6] = v;
  __syncthreads();
  if (t < 16) {
    float x = part[t];
#pragma unroll
    for (int off = 1; off < 16; off <<= 1) x += __shfl_xor(x, off);
    if (t == 0) atomicAdd(&wsf[0], x);
  }
}

__global__ __launch_bounds__(128) void finalize_k(const float* __restrict__ wsf,
                                                  const float* __restrict__ pabs,
                                                  const float* __restrict__ psq,
                                                  float* __restrict__ out) {
  __shared__ float ra[2], rs[2];
  const int t = threadIdx.x;
  float a = pabs[t], s = psq[t];
#pragma unroll
  for (int off = 1; off < 64; off <<= 1) {
    a += __shfl_xor(a, off);
    s += __shfl_xor(s, off);
  }
  if ((t & 63) == 0) { ra[t >> 6] = a; rs[t >> 6] = s; }
  __syncthreads();
  if (t == 0)
    out[0] = wsf[0] * (1.f / (float)BROWS) +
             LAMB_C * ((ra[0] + ra[1]) + sqrtf(rs[0] + rs[1]));
}

extern "C" void kernel_launch(void* const* d_in, const int* in_sizes, int n_in,
                              void* d_out, int out_size, void* d_ws, size_t ws_size,
                              hipStream_t stream) {
  const float* skt  = (const float*)d_in[0];
  const float* imgp = (const float*)d_in[1];
  const float* imgn = (const float*)d_in[2];
  const float* w    = (const float*)d_in[3];

  float* wsf = (float*)d_ws;
  float* colsum = wsf + 16;
  float* pabs = (float*)((char*)d_ws + WS_PABS_OFF);
  float* psq = (float*)((char*)d_ws + WS_PSQ_OFF);
  float* rowacc = (float*)((char*)d_ws + WS_ROWACC_OFF);
  u16* wb = (u16*)((char*)d_ws + WS_WB_OFF);
  u16* sktb = (u16*)((char*)d_ws + WS_SKTB_OFF);
  float* out = (float*)d_out;

  // zero wsf + colsum + rowacc every call (harness doesn't re-poison)
  hipMemsetAsync(d_ws, 0, WS_ROWACC_OFF + BROWS * sizeof(float), stream);

  if (ws_size >= WS_NEED_FULL) {
    prep_all<true><<<128 + 2048, 256, 0, stream>>>(w, skt, colsum, pabs, psq, wb, sktb);
    hofel_main<true><<<512, 512, 0, stream>>>(skt, imgp, imgn, wb, sktb, colsum, rowacc);
  } else {
    prep_all<false><<<128, 256, 0, stream>>>(w, skt, colsum, pabs, psq, wb, sktb);
    hofel_main<false><<<512, 512, 0, stream>>>(skt, imgp, imgn, wb, sktb, colsum, rowacc);
  }

  hinge_reduce<<<16, 1024, 0, stream>>>(rowacc, wsf);
  finalize_k<<<1, 128, 0, stream>>>(wsf, pabs, psq, out);
}